// Round 21
// baseline (258.694 us; speedup 1.0000x reference)
//
#include <hip/hip_runtime.h>
#include <math.h>

#define NB   16
#define NBEF 512
#define NSTK 256
#define CCO  128
#define SPIN 512
#define SPOUT 256
#define DNIN 128
#define DNOUT 128
#define NPNT 32
#define SP_ELEMS (NB * SPOUT * NBEF)   // 2,097,152 f32 elems (sparse output)

typedef __attribute__((ext_vector_type(8))) short bf16x8v;   // 8 bf16 = 4 VGPR
typedef __attribute__((ext_vector_type(4))) float f32x4v;    // MFMA C/D

typedef __attribute__((address_space(1))) const unsigned int* gas1_t;
typedef __attribute__((address_space(3))) unsigned int* las3_t;

__device__ __forceinline__ unsigned short f32_to_bf16(float f) {
    unsigned int u = __float_as_uint(f);
    u += 0x7fffu + ((u >> 16) & 1u);     // round-to-nearest-even
    return (unsigned short)(u >> 16);
}

// gelu(tanh approx) with hw exp2: tanh(z)=sign(z)*(1-2/(2^(2|z|*log2e)+1))
__device__ __forceinline__ float fast_gelu(float x) {
    float z = 0.7978845608028654f * x * (1.0f + 0.044715f * x * x);
    float az = fabsf(z) * 2.885390081777927f;   // 2*log2(e)
    float e;
    asm("v_exp_f32 %0, %1" : "=v"(e) : "v"(az));
    float r = __builtin_amdgcn_rcpf(e + 1.0f);
    float th = copysignf(1.0f - 2.0f * r, z);
    return 0.5f * x * (1.0f + th);
}

// order-preserving float -> uint map
__device__ __forceinline__ unsigned int f2ord(float f) {
    unsigned int u = __float_as_uint(f);
    return (u & 0x80000000u) ? ~u : (u | 0x80000000u);
}
__device__ __forceinline__ float ord2f(unsigned int o) {
    unsigned int u = (o & 0x80000000u) ? (o & 0x7fffffffu) : ~o;
    return __uint_as_float(u);
}

__device__ __forceinline__ unsigned long long wave_min_u64(unsigned long long k) {
    #pragma unroll
    for (int d = 32; d >= 1; d >>= 1) {
        unsigned long long o = __shfl_xor(k, d, 64);
        if (o < k) k = o;
    }
    return k;
}

// ---------------- Kernel 0: tiled 2-NN (v2 — measured best) ----------------
__global__ __launch_bounds__(256) void knn_kernel(
    const float* __restrict__ stk_coor,      // [B][256][128]
    const float* __restrict__ stk_coor_bef,  // [B][512][128]
    int2* __restrict__ idx_out,              // [B][512]
    float2* __restrict__ w_out)              // [B][512]
{
    int b  = blockIdx.y;
    int q0 = blockIdx.x * 16;
    int tid  = threadIdx.x;
    int lane = tid & 63;
    int qg   = tid >> 6;                     // wave id: queries qg*4..+4
    int pg   = lane;                         // points pg*4..+4

    __shared__ float Qt[128][16];            // [c][q] 8 KB
    __shared__ float Pt[32][260];            // [c-chunk][p] 33.3 KB (pad 4)

    {
        int q = tid >> 4, c0 = (tid & 15) * 8;
        const float* src = stk_coor_bef + ((size_t)b * NBEF + q0 + q) * CCO + c0;
        float4 v0 = *reinterpret_cast<const float4*>(src);
        float4 v1 = *reinterpret_cast<const float4*>(src + 4);
        Qt[c0+0][q] = v0.x; Qt[c0+1][q] = v0.y; Qt[c0+2][q] = v0.z; Qt[c0+3][q] = v0.w;
        Qt[c0+4][q] = v1.x; Qt[c0+5][q] = v1.y; Qt[c0+6][q] = v1.z; Qt[c0+7][q] = v1.w;
    }

    float dot[4][4];
    #pragma unroll
    for (int a = 0; a < 4; ++a)
        #pragma unroll
        for (int c = 0; c < 4; ++c) dot[a][c] = 0.f;
    float qn[4] = {0.f, 0.f, 0.f, 0.f};
    float pn[4] = {0.f, 0.f, 0.f, 0.f};

    for (int ct = 0; ct < 4; ++ct) {
        __syncthreads();
        #pragma unroll
        for (int it = 0; it < 8; ++it) {
            int p  = (tid >> 3) + it * 32;
            int cl = (tid & 7) * 4;
            float4 v = *reinterpret_cast<const float4*>(
                stk_coor + ((size_t)b * NSTK + p) * CCO + ct * 32 + cl);
            Pt[cl+0][p] = v.x; Pt[cl+1][p] = v.y; Pt[cl+2][p] = v.z; Pt[cl+3][p] = v.w;
        }
        __syncthreads();
        #pragma unroll 8
        for (int c = 0; c < 32; ++c) {
            float4 qv = *reinterpret_cast<const float4*>(&Qt[ct*32 + c][qg*4]);
            float4 pv = *reinterpret_cast<const float4*>(&Pt[c][pg*4]);
            float qa[4] = {qv.x, qv.y, qv.z, qv.w};
            float pa[4] = {pv.x, pv.y, pv.z, pv.w};
            #pragma unroll
            for (int j = 0; j < 4; ++j) {
                qn[j] += qa[j] * qa[j];
                pn[j] += pa[j] * pa[j];
                #pragma unroll
                for (int k = 0; k < 4; ++k) dot[j][k] += qa[j] * pa[k];
            }
        }
    }

    #pragma unroll
    for (int qj = 0; qj < 4; ++qj) {
        unsigned long long kA = 0xFFFFFFFFFFFFFFFFull, kB = 0xFFFFFFFFFFFFFFFFull;
        #pragma unroll
        for (int pj = 0; pj < 4; ++pj) {
            float d2 = qn[qj] + pn[pj] - 2.f * dot[qj][pj];
            unsigned long long key =
                ((unsigned long long)f2ord(d2) << 32) | (unsigned int)(pg * 4 + pj);
            if (key < kA)      { kB = kA; kA = key; }
            else if (key < kB) { kB = key; }
        }
        unsigned long long m0 = wave_min_u64(kA);
        unsigned long long c2 = (kA == m0) ? kB : kA;
        unsigned long long m1 = wave_min_u64(c2);
        if (lane == 0) {
            float d0 = ord2f((unsigned int)(m0 >> 32));
            float d1 = ord2f((unsigned int)(m1 >> 32));
            int j0 = (int)(m0 & 0xffffffffu), j1 = (int)(m1 & 0xffffffffu);
            float r0 = 1.f / (d0 + 1e-8f);
            float r1 = 1.f / (d1 + 1e-8f);
            float s = r0 + r1;
            int q = q0 + qg * 4 + qj;
            idx_out[b * NBEF + q] = make_int2(j0, j1);
            w_out[b * NBEF + q]   = make_float2(r0 / s, r1 / s);
        }
    }
}

// ---------------- Kernel 1: merged one-time prep (A fragments + w_sp transpose) ----------------
__global__ __launch_bounds__(256) void prep_kernel(
    const float* __restrict__ w_ct,          // [128][128][4]
    const float* __restrict__ w_sp,          // [256][512]
    unsigned short* __restrict__ Aws,        // 65536 bf16
    float4* __restrict__ wTq,                // [128][256] (may be null)
    int do_wt)
{
    if (blockIdx.x < 32) {
        int g = blockIdx.x * 256 + threadIdx.x;  // 0..8191
        int lane = g & 63;
        int ks = (g >> 6) & 7;
        int mt16 = g >> 9;
        int m = mt16 * 16 + (lane & 15);
        int o = m & 127;
        int modd = (m >= 128);
        unsigned short t8[8];
        #pragma unroll
        for (int j = 0; j < 8; ++j) {
            int k = ks * 32 + (lane >> 4) * 8 + j;
            int i = k & 127;
            int tap = modd ? (k < 128 ? 2 : 0) : (k < 128 ? 3 : 1);
            t8[j] = f32_to_bf16(w_ct[((size_t)i * DNOUT + o) * 4 + tap]);
        }
        *reinterpret_cast<uint4*>(Aws + (size_t)g * 8) = *reinterpret_cast<const uint4*>(t8);
    } else if (do_wt) {
        int c4 = blockIdx.x - 32;                // 0..127
        int o  = threadIdx.x;                    // 0..255
        float4 v = *reinterpret_cast<const float4*>(w_sp + (size_t)o * SPIN + c4 * 4);
        wTq[c4 * 256 + o] = v;
    }
}

// ---------------- Kernel M: merged main — dense (x<128) + sparse (x 128..159) ----------------
// Dense: R20 winner staging/epilogue, MFMA now TWO nt-passes (base 0 and 4) with acc[5][2]
// so accumulator residency drops 72 -> 40 regs (unified VGPR/AGPR budget was capping
// occupancy at ~3 waves/SIMD; this raises it to 4).  acc[base+4] recomputed in pass 2 with
// identical FLOP order -> bit-identical output.  Sparse: R20 winner verbatim.
__global__ __launch_bounds__(512, 4) void main_kernel(
    const float* __restrict__ DF,            // [16][128][256][32]
    const float* __restrict__ SF,            // [16][512][256]
    const unsigned short* __restrict__ Aws,  // fragment-linear A
    const float* __restrict__ w_sp,
    const float4* __restrict__ wTq,          // or null
    const float* __restrict__ b_ct,
    const float* __restrict__ gamma_dn,
    const float* __restrict__ beta_dn,
    const float* __restrict__ b_sp,
    const float* __restrict__ gamma_sp,
    const float* __restrict__ beta_sp,
    const int2* __restrict__ idxws, const float2* __restrict__ wgtws,
    float* __restrict__ out)                 // full output base
{
    __shared__ __align__(16) char smem[71808];
    int b   = blockIdx.y;
    int tid  = threadIdx.x;
    const float invs = 1.0f / sqrtf(1.0f + 1e-5f);

    if (blockIdx.x < 128) {
        // ================= DENSE path =================
        float* Y            = (float*)smem;                        // 32768 B
        unsigned short* Xs  = (unsigned short*)(smem + 32768);     // 37376 B
        float* bnb          = (float*)(smem + 70144);
        float* bns          = (float*)(smem + 70656);
        float* bnt          = (float*)(smem + 71168);
        int2*  sij          = (int2*)(smem + 71680);
        float2* swt         = (float2*)(smem + 71728);
        float* outd = out + SP_ELEMS;

        int blk = blockIdx.x;
        int n0  = blk * 4;
        int S0  = n0 * 32;
        int T0  = n0 * 64;
        int lane = tid & 63;
        int wid  = tid >> 6;
        int rit  = lane & 15;
        int kgrp = lane >> 4;

        if (tid < 128) {
            bnb[tid] = b_ct[tid];
            bns[tid] = gamma_dn[tid] * invs;
            bnt[tid] = beta_dn[tid];
        }
        if (tid < 6) {
            int s = n0 - 1 + tid;
            s = (s < 0) ? 0 : ((s > NBEF - 1) ? NBEF - 1 : s);
            sij[tid] = idxws[b * NBEF + s];
            swt[tid] = wgtws[b * NBEF + s];
        }
        if (tid < 256) {
            uint4 z = make_uint4(0, 0, 0, 0);
            *reinterpret_cast<uint4*>(&Xs[130 * 128 + tid * 8]) = z;
        }
        __syncthreads();                     // barrier 1

        const float* DFb = DF + (size_t)b * (DNIN * NSTK * NPNT);

        if (tid < 256) {                     // halo cols 0 and 129
            int i    = tid & 127;
            int side = tid >> 7;
            int col  = side ? 129 : 0;
            int L    = side ? (S0 + 128) : (S0 - 1);
            L = (L < 0) ? 0 : ((L > 16383) ? 16383 : L);
            int stroke = L >> 5, pt = L & 31;
            int slot = stroke - (n0 - 1);
            int2  ij = sij[slot];
            float2 w = swt[slot];
            float v = w.x * DFb[(size_t)i * 8192 + (size_t)ij.x * NPNT + pt]
                    + w.y * DFb[(size_t)i * 8192 + (size_t)ij.y * NPNT + pt];
            int dst = col * 128 + ((((i >> 3) ^ (col & 15))) << 3) + (i & 7);
            Xs[dst] = f32_to_bf16(v);
        }

        // barrier-free per-wave staging
        float* Ysl = &Y[wid * 1024];
        int swq = (lane & 7) ^ ((lane >> 3) & 7);
        int sp2 = lane & 31;
        int so  = lane >> 5;
        int goct = wid * 2 + so;
        #pragma unroll 1
        for (int nl = 0; nl < 4; ++nl) {
            int2 ij = sij[nl + 1];
            #pragma unroll
            for (int p = 0; p < 2; ++p) {
                int jj = p ? ij.y : ij.x;
                #pragma unroll
                for (int q = 0; q < 2; ++q) {
                    int i = 16 * wid + q * 8 + (lane >> 3);
                    const float* g = DFb + (size_t)i * 8192 + (size_t)jj * NPNT + (swq << 2);
                    __builtin_amdgcn_global_load_lds((gas1_t)(const void*)g,
                        (las3_t)(void*)&Ysl[p * 512 + q * 256], 16, 0, 0);
                }
            }
            asm volatile("s_waitcnt vmcnt(0)" ::: "memory");
            __builtin_amdgcn_sched_barrier(0);
            {
                float2 w = swt[nl + 1];
                unsigned short t8[8];
                #pragma unroll
                for (int pp = 0; pp < 8; ++pp) {
                    int a = (so * 8 + pp) * 32 + (((sp2 >> 2) ^ pp) << 2) + (sp2 & 3);
                    float v = w.x * Ysl[a] + w.y * Ysl[512 + a];
                    t8[pp] = f32_to_bf16(v);
                }
                int col = nl * 32 + sp2 + 1;
                int dst = col * 128 + ((goct ^ (col & 15)) << 3);
                *reinterpret_cast<uint4*>(&Xs[dst]) = *reinterpret_cast<const uint4*>(t8);
            }
        }
        __syncthreads();                     // barrier 2: Xs ready

        // MFMA + epilogue in TWO passes (base = 0, 4): acc[5][2] resident per pass
        int srcl = (lane & 48) | ((lane + 1) & 15);
        #pragma unroll 1
        for (int base = 0; base <= 4; base += 4) {
            f32x4v acc[5][2];
            #pragma unroll
            for (int nt = 0; nt < 5; ++nt) {
                acc[nt][0] = (f32x4v){0.f, 0.f, 0.f, 0.f};
                acc[nt][1] = (f32x4v){0.f, 0.f, 0.f, 0.f};
            }
            #pragma unroll
            for (int kh = 0; kh < 2; ++kh) {
                bf16x8v af[2][4];
                #pragma unroll
                for (int mt = 0; mt < 2; ++mt) {
                    int mt16 = wid + mt * 8;
                    #pragma unroll
                    for (int k4 = 0; k4 < 4; ++k4) {
                        int ks = kh * 4 + k4;
                        af[mt][k4] = *reinterpret_cast<const bf16x8v*>(
                            Aws + (((size_t)(mt16 * 8 + ks)) * 64 + lane) * 8);
                    }
                }
                #pragma unroll
                for (int k4 = 0; k4 < 4; ++k4) {
                    int ks   = kh * 4 + k4;
                    int kb   = ks * 32 + kgrp * 8;
                    int half = kb >> 7;
                    int i    = kb & 127;
                    #pragma unroll
                    for (int nt = 0; nt < 5; ++nt) {
                        int col = (base + nt) * 16 + rit + half;
                        int src = col * 128 + ((((i >> 3) ^ (col & 15))) << 3);
                        bf16x8v bfrag = *reinterpret_cast<const bf16x8v*>(&Xs[src]);
                        acc[nt][0] = __builtin_amdgcn_mfma_f32_16x16x32_bf16(af[0][k4], bfrag, acc[nt][0], 0, 0, 0);
                        acc[nt][1] = __builtin_amdgcn_mfma_f32_16x16x32_bf16(af[1][k4], bfrag, acc[nt][1], 0, 0, 0);
                    }
                }
            }
            // seam-free epilogue for local nt 0..3 (global nt = base+nt < 8)
            #pragma unroll
            for (int nt = 0; nt < 4; ++nt) {
                int c = (base + nt) * 16 + rit;
                #pragma unroll
                for (int q = 0; q < 4; ++q) {
                    float srcv = (rit == 0) ? acc[nt + 1][1][q] : acc[nt][1][q];
                    float a1n = __shfl(srcv, srcl, 64);
                    int o = wid * 16 + kgrp * 4 + q;
                    float bias = bnb[o], scale = bns[o], beta = bnt[o];
                    float ye = fast_gelu((acc[nt][0][q] + bias) * scale + beta);
                    float yo = fast_gelu((a1n + bias) * scale + beta);
                    size_t rowbase = (((size_t)b * DNOUT + o) << 15) + (size_t)T0;
                    *reinterpret_cast<float2*>(outd + rowbase + 2 * c) = make_float2(ye, yo);
                }
            }
        }
    } else {
        // ================= SPARSE path (2 groups x 8 n's) =================
        float*  fsb  = (float*)smem;                      // fs[2][512][8] = 32768 B
        int2*   ssij = (int2*)(smem + 32768);             // [16]
        float2* sswt = (float2*)(smem + 32896);           // [16]

        int sx = blockIdx.x - 128;                        // 0..31
        int tid256 = tid & 255;
        int group  = tid >> 8;                            // 0/1
        int n0 = sx * 16 + group * 8;

        if (tid < 16) {
            ssij[tid] = idxws[b * NBEF + sx * 16 + tid];
            sswt[tid] = wgtws[b * NBEF + sx * 16 + tid];
        }
        __syncthreads();

        float* fsg = fsb + group * 4096;
        for (int l = tid256; l < SPIN * 8; l += 256) {
            int c = l >> 3, nn = l & 7;
            int2  ij = ssij[group * 8 + nn];
            float2 w = sswt[group * 8 + nn];
            const float* row = SF + ((size_t)b * SPIN + c) * NSTK;
            fsg[l] = w.x * row[ij.x] + w.y * row[ij.y];
        }
        __syncthreads();

        int o = tid256;
        float acc[8] = {0,0,0,0,0,0,0,0};
        #pragma unroll 2
        for (int c4 = 0; c4 < SPIN / 4; ++c4) {
            float4 a = wTq ? wTq[c4 * 256 + o]
                           : *reinterpret_cast<const float4*>(w_sp + (size_t)o * SPIN + c4 * 4);
            int c = c4 * 4;
            float4 fA[4], fB[4];
            #pragma unroll
            for (int k = 0; k < 4; ++k) {
                fA[k] = *reinterpret_cast<const float4*>(&fsg[(c + k) * 8]);
                fB[k] = *reinterpret_cast<const float4*>(&fsg[(c + k) * 8 + 4]);
            }
            const float* a4 = reinterpret_cast<const float*>(&a);
            #pragma unroll
            for (int nn = 0; nn < 4; ++nn) {
                float sA = 0.f, sB = 0.f;
                #pragma unroll
                for (int k = 0; k < 4; ++k) {
                    sA += a4[k] * reinterpret_cast<const float*>(&fA[k])[nn];
                    sB += a4[k] * reinterpret_cast<const float*>(&fB[k])[nn];
                }
                acc[nn]     += sA;
                acc[nn + 4] += sB;
            }
        }

        float bias  = b_sp[o];
        float scale = gamma_sp[o] * invs;
        float beta  = beta_sp[o];
        float r[8];
        #pragma unroll
        for (int q = 0; q < 8; ++q)
            r[q] = fast_gelu((acc[q] + bias) * scale + beta);
        float* dst = out + ((size_t)b * SPOUT + o) * NBEF + n0;
        *reinterpret_cast<float4*>(dst)     = make_float4(r[0], r[1], r[2], r[3]);
        *reinterpret_cast<float4*>(dst + 4) = make_float4(r[4], r[5], r[6], r[7]);
    }
}

extern "C" void kernel_launch(void* const* d_in, const int* in_sizes, int n_in,
                              void* d_out, int out_size, void* d_ws, size_t ws_size,
                              hipStream_t stream) {
    const float* sparse_fea   = (const float*)d_in[0];
    const float* dense_fea    = (const float*)d_in[1];
    const float* stk_coor     = (const float*)d_in[2];
    const float* stk_coor_bef = (const float*)d_in[3];
    const float* w_sp     = (const float*)d_in[4];
    const float* b_sp     = (const float*)d_in[5];
    const float* gamma_sp = (const float*)d_in[6];
    const float* beta_sp  = (const float*)d_in[7];
    const float* w_ct     = (const float*)d_in[8];
    const float* b_ct     = (const float*)d_in[9];
    const float* gamma_dn = (const float*)d_in[10];
    const float* beta_dn  = (const float*)d_in[11];
    float* out = (float*)d_out;

    char* ws = (char*)d_ws;
    int2*   idx = (int2*)ws;                               // 64 KB
    float2* wgt = (float2*)(ws + 65536);                   // 64 KB
    unsigned short* Aws = (unsigned short*)(ws + 131072);  // 128 KB
    bool use_wt = (ws_size >= 786432);                     // + 512 KB wTq = 768 KB total
    float4* wTq = use_wt ? (float4*)(ws + 262144) : nullptr;

    knn_kernel<<<dim3(NBEF / 16, NB), 256, 0, stream>>>(stk_coor, stk_coor_bef, idx, wgt);
    prep_kernel<<<use_wt ? 160 : 32, 256, 0, stream>>>(w_ct, w_sp, Aws, wTq, use_wt ? 1 : 0);
    main_kernel<<<dim3(160, NB), 512, 0, stream>>>(
        dense_fea, sparse_fea, Aws, w_sp, wTq,
        b_ct, gamma_dn, beta_dn, b_sp, gamma_sp, beta_sp,
        idx, wgt, out);
}

// Round 22
// 195.699 us; speedup vs baseline: 1.3219x; 1.3219x over previous
//
#include <hip/hip_runtime.h>
#include <math.h>

#define NB   16
#define NBEF 512
#define NSTK 256
#define CCO  128
#define SPIN 512
#define SPOUT 256
#define DNIN 128
#define DNOUT 128
#define NPNT 32
#define SP_ELEMS (NB * SPOUT * NBEF)   // 2,097,152 f32 elems (sparse output)

typedef __attribute__((ext_vector_type(8))) short bf16x8v;   // 8 bf16 = 4 VGPR
typedef __attribute__((ext_vector_type(4))) float f32x4v;    // MFMA C/D

typedef __attribute__((address_space(1))) const unsigned int* gas1_t;
typedef __attribute__((address_space(3))) unsigned int* las3_t;

__device__ __forceinline__ unsigned short f32_to_bf16(float f) {
    unsigned int u = __float_as_uint(f);
    u += 0x7fffu + ((u >> 16) & 1u);     // round-to-nearest-even
    return (unsigned short)(u >> 16);
}

// gelu(tanh approx) with hw exp2: tanh(z)=sign(z)*(1-2/(2^(2|z|*log2e)+1))
__device__ __forceinline__ float fast_gelu(float x) {
    float z = 0.7978845608028654f * x * (1.0f + 0.044715f * x * x);
    float az = fabsf(z) * 2.885390081777927f;   // 2*log2(e)
    float e;
    asm("v_exp_f32 %0, %1" : "=v"(e) : "v"(az));
    float r = __builtin_amdgcn_rcpf(e + 1.0f);
    float th = copysignf(1.0f - 2.0f * r, z);
    return 0.5f * x * (1.0f + th);
}

// order-preserving float -> uint map
__device__ __forceinline__ unsigned int f2ord(float f) {
    unsigned int u = __float_as_uint(f);
    return (u & 0x80000000u) ? ~u : (u | 0x80000000u);
}
__device__ __forceinline__ float ord2f(unsigned int o) {
    unsigned int u = (o & 0x80000000u) ? (o & 0x7fffffffu) : ~o;
    return __uint_as_float(u);
}

__device__ __forceinline__ unsigned long long wave_min_u64(unsigned long long k) {
    #pragma unroll
    for (int d = 32; d >= 1; d >>= 1) {
        unsigned long long o = __shfl_xor(k, d, 64);
        if (o < k) k = o;
    }
    return k;
}

// ---------------- Kernel 0: merged kNN (x<32) + one-time prep (x>=32) ----------------
__global__ __launch_bounds__(256) void knn_prep_kernel(
    const float* __restrict__ stk_coor,      // [B][256][128]
    const float* __restrict__ stk_coor_bef,  // [B][512][128]
    const float* __restrict__ w_ct,          // [128][128][4]
    const float* __restrict__ w_sp,          // [256][512]
    int2* __restrict__ idx_out,              // [B][512]
    float2* __restrict__ w_out,              // [B][512]
    unsigned short* __restrict__ Aws,        // 65536 bf16
    float4* __restrict__ wTq,                // [128][256] (may be null)
    int do_wt)
{
    int b   = blockIdx.y;
    int tid = threadIdx.x;

    if (blockIdx.x >= 32) {
        // ---- prep block j = (x-32)*16 + b  (j in 0..159) ----
        int j = (blockIdx.x - 32) * 16 + b;
        if (j < 32) {
            int g = j * 256 + tid;               // 0..8191
            int lane = g & 63;
            int ks = (g >> 6) & 7;
            int mt16 = g >> 9;
            int m = mt16 * 16 + (lane & 15);
            int o = m & 127;
            int modd = (m >= 128);
            unsigned short t8[8];
            #pragma unroll
            for (int jj = 0; jj < 8; ++jj) {
                int k = ks * 32 + (lane >> 4) * 8 + jj;
                int i = k & 127;
                int tap = modd ? (k < 128 ? 2 : 0) : (k < 128 ? 3 : 1);
                t8[jj] = f32_to_bf16(w_ct[((size_t)i * DNOUT + o) * 4 + tap]);
            }
            *reinterpret_cast<uint4*>(Aws + (size_t)g * 8) = *reinterpret_cast<const uint4*>(t8);
        } else if (do_wt) {
            int c4 = j - 32;                     // 0..127
            int o  = tid;                        // 0..255
            float4 v = *reinterpret_cast<const float4*>(w_sp + (size_t)o * SPIN + c4 * 4);
            wTq[c4 * 256 + o] = v;
        }
        return;
    }

    // ---- kNN path (R20 winner verbatim) ----
    int q0 = blockIdx.x * 16;
    int lane = tid & 63;
    int qg   = tid >> 6;                     // wave id: queries qg*4..+4
    int pg   = lane;                         // points pg*4..+4

    __shared__ float Qt[128][16];            // [c][q] 8 KB
    __shared__ float Pt[32][260];            // [c-chunk][p] 33.3 KB (pad 4)

    {
        int q = tid >> 4, c0 = (tid & 15) * 8;
        const float* src = stk_coor_bef + ((size_t)b * NBEF + q0 + q) * CCO + c0;
        float4 v0 = *reinterpret_cast<const float4*>(src);
        float4 v1 = *reinterpret_cast<const float4*>(src + 4);
        Qt[c0+0][q] = v0.x; Qt[c0+1][q] = v0.y; Qt[c0+2][q] = v0.z; Qt[c0+3][q] = v0.w;
        Qt[c0+4][q] = v1.x; Qt[c0+5][q] = v1.y; Qt[c0+6][q] = v1.z; Qt[c0+7][q] = v1.w;
    }

    float dot[4][4];
    #pragma unroll
    for (int a = 0; a < 4; ++a)
        #pragma unroll
        for (int c = 0; c < 4; ++c) dot[a][c] = 0.f;
    float qn[4] = {0.f, 0.f, 0.f, 0.f};
    float pn[4] = {0.f, 0.f, 0.f, 0.f};

    for (int ct = 0; ct < 4; ++ct) {
        __syncthreads();
        #pragma unroll
        for (int it = 0; it < 8; ++it) {
            int p  = (tid >> 3) + it * 32;
            int cl = (tid & 7) * 4;
            float4 v = *reinterpret_cast<const float4*>(
                stk_coor + ((size_t)b * NSTK + p) * CCO + ct * 32 + cl);
            Pt[cl+0][p] = v.x; Pt[cl+1][p] = v.y; Pt[cl+2][p] = v.z; Pt[cl+3][p] = v.w;
        }
        __syncthreads();
        #pragma unroll 8
        for (int c = 0; c < 32; ++c) {
            float4 qv = *reinterpret_cast<const float4*>(&Qt[ct*32 + c][qg*4]);
            float4 pv = *reinterpret_cast<const float4*>(&Pt[c][pg*4]);
            float qa[4] = {qv.x, qv.y, qv.z, qv.w};
            float pa[4] = {pv.x, pv.y, pv.z, pv.w};
            #pragma unroll
            for (int j = 0; j < 4; ++j) {
                qn[j] += qa[j] * qa[j];
                pn[j] += pa[j] * pa[j];
                #pragma unroll
                for (int k = 0; k < 4; ++k) dot[j][k] += qa[j] * pa[k];
            }
        }
    }

    #pragma unroll
    for (int qj = 0; qj < 4; ++qj) {
        unsigned long long kA = 0xFFFFFFFFFFFFFFFFull, kB = 0xFFFFFFFFFFFFFFFFull;
        #pragma unroll
        for (int pj = 0; pj < 4; ++pj) {
            float d2 = qn[qj] + pn[pj] - 2.f * dot[qj][pj];
            unsigned long long key =
                ((unsigned long long)f2ord(d2) << 32) | (unsigned int)(pg * 4 + pj);
            if (key < kA)      { kB = kA; kA = key; }
            else if (key < kB) { kB = key; }
        }
        unsigned long long m0 = wave_min_u64(kA);
        unsigned long long c2 = (kA == m0) ? kB : kA;
        unsigned long long m1 = wave_min_u64(c2);
        if (lane == 0) {
            float d0 = ord2f((unsigned int)(m0 >> 32));
            float d1 = ord2f((unsigned int)(m1 >> 32));
            int j0 = (int)(m0 & 0xffffffffu), j1 = (int)(m1 & 0xffffffffu);
            float r0 = 1.f / (d0 + 1e-8f);
            float r1 = 1.f / (d1 + 1e-8f);
            float s = r0 + r1;
            int q = q0 + qg * 4 + qj;
            idx_out[b * NBEF + q] = make_int2(j0, j1);
            w_out[b * NBEF + q]   = make_float2(r0 / s, r1 / s);
        }
    }
}

// ---------------- Kernel M: merged main — dense (x<128) + sparse (x 128..159) ----------------
// R20 winner verbatim: dense = barrier-free per-wave staging, ks-outer acc[9][2]-resident
// MFMA, seam-free full-line epilogue; sparse = b128-vectorized fs + coalesced wTq.
__global__ __launch_bounds__(512, 4) void main_kernel(
    const float* __restrict__ DF,            // [16][128][256][32]
    const float* __restrict__ SF,            // [16][512][256]
    const unsigned short* __restrict__ Aws,  // fragment-linear A
    const float* __restrict__ w_sp,
    const float4* __restrict__ wTq,          // or null
    const float* __restrict__ b_ct,
    const float* __restrict__ gamma_dn,
    const float* __restrict__ beta_dn,
    const float* __restrict__ b_sp,
    const float* __restrict__ gamma_sp,
    const float* __restrict__ beta_sp,
    const int2* __restrict__ idxws, const float2* __restrict__ wgtws,
    float* __restrict__ out)                 // full output base
{
    __shared__ __align__(16) char smem[71808];
    int b   = blockIdx.y;
    int tid  = threadIdx.x;
    const float invs = 1.0f / sqrtf(1.0f + 1e-5f);

    if (blockIdx.x < 128) {
        // ================= DENSE path =================
        float* Y            = (float*)smem;                        // 32768 B
        unsigned short* Xs  = (unsigned short*)(smem + 32768);     // 37376 B
        float* bnb          = (float*)(smem + 70144);
        float* bns          = (float*)(smem + 70656);
        float* bnt          = (float*)(smem + 71168);
        int2*  sij          = (int2*)(smem + 71680);
        float2* swt         = (float2*)(smem + 71728);
        float* outd = out + SP_ELEMS;

        int blk = blockIdx.x;
        int n0  = blk * 4;
        int S0  = n0 * 32;
        int T0  = n0 * 64;
        int lane = tid & 63;
        int wid  = tid >> 6;
        int rit  = lane & 15;
        int kgrp = lane >> 4;

        if (tid < 128) {
            bnb[tid] = b_ct[tid];
            bns[tid] = gamma_dn[tid] * invs;
            bnt[tid] = beta_dn[tid];
        }
        if (tid < 6) {
            int s = n0 - 1 + tid;
            s = (s < 0) ? 0 : ((s > NBEF - 1) ? NBEF - 1 : s);
            sij[tid] = idxws[b * NBEF + s];
            swt[tid] = wgtws[b * NBEF + s];
        }
        if (tid < 256) {
            uint4 z = make_uint4(0, 0, 0, 0);
            *reinterpret_cast<uint4*>(&Xs[130 * 128 + tid * 8]) = z;
        }
        __syncthreads();                     // barrier 1

        const float* DFb = DF + (size_t)b * (DNIN * NSTK * NPNT);

        if (tid < 256) {                     // halo cols 0 and 129
            int i    = tid & 127;
            int side = tid >> 7;
            int col  = side ? 129 : 0;
            int L    = side ? (S0 + 128) : (S0 - 1);
            L = (L < 0) ? 0 : ((L > 16383) ? 16383 : L);
            int stroke = L >> 5, pt = L & 31;
            int slot = stroke - (n0 - 1);
            int2  ij = sij[slot];
            float2 w = swt[slot];
            float v = w.x * DFb[(size_t)i * 8192 + (size_t)ij.x * NPNT + pt]
                    + w.y * DFb[(size_t)i * 8192 + (size_t)ij.y * NPNT + pt];
            int dst = col * 128 + ((((i >> 3) ^ (col & 15))) << 3) + (i & 7);
            Xs[dst] = f32_to_bf16(v);
        }

        // barrier-free per-wave staging
        float* Ysl = &Y[wid * 1024];
        int swq = (lane & 7) ^ ((lane >> 3) & 7);
        int sp2 = lane & 31;
        int so  = lane >> 5;
        int goct = wid * 2 + so;
        #pragma unroll 1
        for (int nl = 0; nl < 4; ++nl) {
            int2 ij = sij[nl + 1];
            #pragma unroll
            for (int p = 0; p < 2; ++p) {
                int jj = p ? ij.y : ij.x;
                #pragma unroll
                for (int q = 0; q < 2; ++q) {
                    int i = 16 * wid + q * 8 + (lane >> 3);
                    const float* g = DFb + (size_t)i * 8192 + (size_t)jj * NPNT + (swq << 2);
                    __builtin_amdgcn_global_load_lds((gas1_t)(const void*)g,
                        (las3_t)(void*)&Ysl[p * 512 + q * 256], 16, 0, 0);
                }
            }
            asm volatile("s_waitcnt vmcnt(0)" ::: "memory");
            __builtin_amdgcn_sched_barrier(0);
            {
                float2 w = swt[nl + 1];
                unsigned short t8[8];
                #pragma unroll
                for (int pp = 0; pp < 8; ++pp) {
                    int a = (so * 8 + pp) * 32 + (((sp2 >> 2) ^ pp) << 2) + (sp2 & 3);
                    float v = w.x * Ysl[a] + w.y * Ysl[512 + a];
                    t8[pp] = f32_to_bf16(v);
                }
                int col = nl * 32 + sp2 + 1;
                int dst = col * 128 + ((goct ^ (col & 15)) << 3);
                *reinterpret_cast<uint4*>(&Xs[dst]) = *reinterpret_cast<const uint4*>(t8);
            }
        }
        __syncthreads();                     // barrier 2: Xs ready

        // MFMA: ks-outer / nt-inner, acc[9][2] resident
        f32x4v acc[9][2];
        #pragma unroll
        for (int nt = 0; nt < 9; ++nt) {
            acc[nt][0] = (f32x4v){0.f, 0.f, 0.f, 0.f};
            acc[nt][1] = (f32x4v){0.f, 0.f, 0.f, 0.f};
        }
        #pragma unroll
        for (int kh = 0; kh < 2; ++kh) {
            bf16x8v af[2][4];
            #pragma unroll
            for (int mt = 0; mt < 2; ++mt) {
                int mt16 = wid + mt * 8;
                #pragma unroll
                for (int k4 = 0; k4 < 4; ++k4) {
                    int ks = kh * 4 + k4;
                    af[mt][k4] = *reinterpret_cast<const bf16x8v*>(
                        Aws + (((size_t)(mt16 * 8 + ks)) * 64 + lane) * 8);
                }
            }
            #pragma unroll
            for (int k4 = 0; k4 < 4; ++k4) {
                int ks   = kh * 4 + k4;
                int kb   = ks * 32 + kgrp * 8;
                int half = kb >> 7;
                int i    = kb & 127;
                #pragma unroll
                for (int nt = 0; nt < 9; ++nt) {
                    int col = nt * 16 + rit + half;
                    int src = col * 128 + ((((i >> 3) ^ (col & 15))) << 3);
                    bf16x8v bfrag = *reinterpret_cast<const bf16x8v*>(&Xs[src]);
                    acc[nt][0] = __builtin_amdgcn_mfma_f32_16x16x32_bf16(af[0][k4], bfrag, acc[nt][0], 0, 0, 0);
                    acc[nt][1] = __builtin_amdgcn_mfma_f32_16x16x32_bf16(af[1][k4], bfrag, acc[nt][1], 0, 0, 0);
                }
            }
        }

        // seam-free epilogue
        int srcl = (lane & 48) | ((lane + 1) & 15);
        #pragma unroll
        for (int nt = 0; nt < 8; ++nt) {
            int c = nt * 16 + rit;
            #pragma unroll
            for (int q = 0; q < 4; ++q) {
                float srcv = (rit == 0) ? acc[nt + 1][1][q] : acc[nt][1][q];
                float a1n = __shfl(srcv, srcl, 64);
                int o = wid * 16 + kgrp * 4 + q;
                float bias = bnb[o], scale = bns[o], beta = bnt[o];
                float ye = fast_gelu((acc[nt][0][q] + bias) * scale + beta);
                float yo = fast_gelu((a1n + bias) * scale + beta);
                size_t rowbase = (((size_t)b * DNOUT + o) << 15) + (size_t)T0;
                *reinterpret_cast<float2*>(outd + rowbase + 2 * c) = make_float2(ye, yo);
            }
        }
    } else {
        // ================= SPARSE path (2 groups x 8 n's) =================
        float*  fsb  = (float*)smem;                      // fs[2][512][8] = 32768 B
        int2*   ssij = (int2*)(smem + 32768);             // [16]
        float2* sswt = (float2*)(smem + 32896);           // [16]

        int sx = blockIdx.x - 128;                        // 0..31
        int tid256 = tid & 255;
        int group  = tid >> 8;                            // 0/1
        int n0 = sx * 16 + group * 8;

        if (tid < 16) {
            ssij[tid] = idxws[b * NBEF + sx * 16 + tid];
            sswt[tid] = wgtws[b * NBEF + sx * 16 + tid];
        }
        __syncthreads();

        float* fsg = fsb + group * 4096;
        for (int l = tid256; l < SPIN * 8; l += 256) {
            int c = l >> 3, nn = l & 7;
            int2  ij = ssij[group * 8 + nn];
            float2 w = sswt[group * 8 + nn];
            const float* row = SF + ((size_t)b * SPIN + c) * NSTK;
            fsg[l] = w.x * row[ij.x] + w.y * row[ij.y];
        }
        __syncthreads();

        int o = tid256;
        float acc[8] = {0,0,0,0,0,0,0,0};
        #pragma unroll 2
        for (int c4 = 0; c4 < SPIN / 4; ++c4) {
            float4 a = wTq ? wTq[c4 * 256 + o]
                           : *reinterpret_cast<const float4*>(w_sp + (size_t)o * SPIN + c4 * 4);
            int c = c4 * 4;
            float4 fA[4], fB[4];
            #pragma unroll
            for (int k = 0; k < 4; ++k) {
                fA[k] = *reinterpret_cast<const float4*>(&fsg[(c + k) * 8]);
                fB[k] = *reinterpret_cast<const float4*>(&fsg[(c + k) * 8 + 4]);
            }
            const float* a4 = reinterpret_cast<const float*>(&a);
            #pragma unroll
            for (int nn = 0; nn < 4; ++nn) {
                float sA = 0.f, sB = 0.f;
                #pragma unroll
                for (int k = 0; k < 4; ++k) {
                    sA += a4[k] * reinterpret_cast<const float*>(&fA[k])[nn];
                    sB += a4[k] * reinterpret_cast<const float*>(&fB[k])[nn];
                }
                acc[nn]     += sA;
                acc[nn + 4] += sB;
            }
        }

        float bias  = b_sp[o];
        float scale = gamma_sp[o] * invs;
        float beta  = beta_sp[o];
        float r[8];
        #pragma unroll
        for (int q = 0; q < 8; ++q)
            r[q] = fast_gelu((acc[q] + bias) * scale + beta);
        float* dst = out + ((size_t)b * SPOUT + o) * NBEF + n0;
        *reinterpret_cast<float4*>(dst)     = make_float4(r[0], r[1], r[2], r[3]);
        *reinterpret_cast<float4*>(dst + 4) = make_float4(r[4], r[5], r[6], r[7]);
    }
}

extern "C" void kernel_launch(void* const* d_in, const int* in_sizes, int n_in,
                              void* d_out, int out_size, void* d_ws, size_t ws_size,
                              hipStream_t stream) {
    const float* sparse_fea   = (const float*)d_in[0];
    const float* dense_fea    = (const float*)d_in[1];
    const float* stk_coor     = (const float*)d_in[2];
    const float* stk_coor_bef = (const float*)d_in[3];
    const float* w_sp     = (const float*)d_in[4];
    const float* b_sp     = (const float*)d_in[5];
    const float* gamma_sp = (const float*)d_in[6];
    const float* beta_sp  = (const float*)d_in[7];
    const float* w_ct     = (const float*)d_in[8];
    const float* b_ct     = (const float*)d_in[9];
    const float* gamma_dn = (const float*)d_in[10];
    const float* beta_dn  = (const float*)d_in[11];
    float* out = (float*)d_out;

    char* ws = (char*)d_ws;
    int2*   idx = (int2*)ws;                               // 64 KB
    float2* wgt = (float2*)(ws + 65536);                   // 64 KB
    unsigned short* Aws = (unsigned short*)(ws + 131072);  // 128 KB
    bool use_wt = (ws_size >= 786432);                     // + 512 KB wTq = 768 KB total
    float4* wTq = use_wt ? (float4*)(ws + 262144) : nullptr;

    knn_prep_kernel<<<dim3(42, NB), 256, 0, stream>>>(
        stk_coor, stk_coor_bef, w_ct, w_sp, idx, wgt, Aws, wTq, use_wt ? 1 : 0);
    main_kernel<<<dim3(160, NB), 512, 0, stream>>>(
        dense_fea, sparse_fea, Aws, w_sp, wTq,
        b_ct, gamma_dn, beta_dn, b_sp, gamma_sp, beta_sp,
        idx, wgt, out);
}

// Round 23
// 192.917 us; speedup vs baseline: 1.3410x; 1.0144x over previous
//
#include <hip/hip_runtime.h>
#include <math.h>

#define NB   16
#define NBEF 512
#define NSTK 256
#define CCO  128
#define SPIN 512
#define SPOUT 256
#define DNIN 128
#define DNOUT 128
#define NPNT 32
#define SP_ELEMS (NB * SPOUT * NBEF)   // 2,097,152 f32 elems (sparse output)

typedef __attribute__((ext_vector_type(8))) short bf16x8v;   // 8 bf16 = 4 VGPR
typedef __attribute__((ext_vector_type(4))) float f32x4v;    // MFMA C/D

typedef __attribute__((address_space(1))) const unsigned int* gas1_t;
typedef __attribute__((address_space(3))) unsigned int* las3_t;

__device__ __forceinline__ unsigned short f32_to_bf16(float f) {
    unsigned int u = __float_as_uint(f);
    u += 0x7fffu + ((u >> 16) & 1u);     // round-to-nearest-even
    return (unsigned short)(u >> 16);
}

// gelu(tanh approx) with hw exp2: tanh(z)=sign(z)*(1-2/(2^(2|z|*log2e)+1))
__device__ __forceinline__ float fast_gelu(float x) {
    float z = 0.7978845608028654f * x * (1.0f + 0.044715f * x * x);
    float az = fabsf(z) * 2.885390081777927f;   // 2*log2(e)
    float e;
    asm("v_exp_f32 %0, %1" : "=v"(e) : "v"(az));
    float r = __builtin_amdgcn_rcpf(e + 1.0f);
    float th = copysignf(1.0f - 2.0f * r, z);
    return 0.5f * x * (1.0f + th);
}

// order-preserving float -> uint map
__device__ __forceinline__ unsigned int f2ord(float f) {
    unsigned int u = __float_as_uint(f);
    return (u & 0x80000000u) ? ~u : (u | 0x80000000u);
}
__device__ __forceinline__ float ord2f(unsigned int o) {
    unsigned int u = (o & 0x80000000u) ? (o & 0x7fffffffu) : ~o;
    return __uint_as_float(u);
}

__device__ __forceinline__ unsigned long long wave_min_u64(unsigned long long k) {
    #pragma unroll
    for (int d = 32; d >= 1; d >>= 1) {
        unsigned long long o = __shfl_xor(k, d, 64);
        if (o < k) k = o;
    }
    return k;
}

// ---------------- Kernel 0: tiled 2-NN (v2 — measured best) ----------------
__global__ __launch_bounds__(256) void knn_kernel(
    const float* __restrict__ stk_coor,      // [B][256][128]
    const float* __restrict__ stk_coor_bef,  // [B][512][128]
    int2* __restrict__ idx_out,              // [B][512]
    float2* __restrict__ w_out)              // [B][512]
{
    int b  = blockIdx.y;
    int q0 = blockIdx.x * 16;
    int tid  = threadIdx.x;
    int lane = tid & 63;
    int qg   = tid >> 6;                     // wave id: queries qg*4..+4
    int pg   = lane;                         // points pg*4..+4

    __shared__ float Qt[128][16];            // [c][q] 8 KB
    __shared__ float Pt[32][260];            // [c-chunk][p] 33.3 KB (pad 4)

    {
        int q = tid >> 4, c0 = (tid & 15) * 8;
        const float* src = stk_coor_bef + ((size_t)b * NBEF + q0 + q) * CCO + c0;
        float4 v0 = *reinterpret_cast<const float4*>(src);
        float4 v1 = *reinterpret_cast<const float4*>(src + 4);
        Qt[c0+0][q] = v0.x; Qt[c0+1][q] = v0.y; Qt[c0+2][q] = v0.z; Qt[c0+3][q] = v0.w;
        Qt[c0+4][q] = v1.x; Qt[c0+5][q] = v1.y; Qt[c0+6][q] = v1.z; Qt[c0+7][q] = v1.w;
    }

    float dot[4][4];
    #pragma unroll
    for (int a = 0; a < 4; ++a)
        #pragma unroll
        for (int c = 0; c < 4; ++c) dot[a][c] = 0.f;
    float qn[4] = {0.f, 0.f, 0.f, 0.f};
    float pn[4] = {0.f, 0.f, 0.f, 0.f};

    for (int ct = 0; ct < 4; ++ct) {
        __syncthreads();
        #pragma unroll
        for (int it = 0; it < 8; ++it) {
            int p  = (tid >> 3) + it * 32;
            int cl = (tid & 7) * 4;
            float4 v = *reinterpret_cast<const float4*>(
                stk_coor + ((size_t)b * NSTK + p) * CCO + ct * 32 + cl);
            Pt[cl+0][p] = v.x; Pt[cl+1][p] = v.y; Pt[cl+2][p] = v.z; Pt[cl+3][p] = v.w;
        }
        __syncthreads();
        #pragma unroll 8
        for (int c = 0; c < 32; ++c) {
            float4 qv = *reinterpret_cast<const float4*>(&Qt[ct*32 + c][qg*4]);
            float4 pv = *reinterpret_cast<const float4*>(&Pt[c][pg*4]);
            float qa[4] = {qv.x, qv.y, qv.z, qv.w};
            float pa[4] = {pv.x, pv.y, pv.z, pv.w};
            #pragma unroll
            for (int j = 0; j < 4; ++j) {
                qn[j] += qa[j] * qa[j];
                pn[j] += pa[j] * pa[j];
                #pragma unroll
                for (int k = 0; k < 4; ++k) dot[j][k] += qa[j] * pa[k];
            }
        }
    }

    #pragma unroll
    for (int qj = 0; qj < 4; ++qj) {
        unsigned long long kA = 0xFFFFFFFFFFFFFFFFull, kB = 0xFFFFFFFFFFFFFFFFull;
        #pragma unroll
        for (int pj = 0; pj < 4; ++pj) {
            float d2 = qn[qj] + pn[pj] - 2.f * dot[qj][pj];
            unsigned long long key =
                ((unsigned long long)f2ord(d2) << 32) | (unsigned int)(pg * 4 + pj);
            if (key < kA)      { kB = kA; kA = key; }
            else if (key < kB) { kB = key; }
        }
        unsigned long long m0 = wave_min_u64(kA);
        unsigned long long c2 = (kA == m0) ? kB : kA;
        unsigned long long m1 = wave_min_u64(c2);
        if (lane == 0) {
            float d0 = ord2f((unsigned int)(m0 >> 32));
            float d1 = ord2f((unsigned int)(m1 >> 32));
            int j0 = (int)(m0 & 0xffffffffu), j1 = (int)(m1 & 0xffffffffu);
            float r0 = 1.f / (d0 + 1e-8f);
            float r1 = 1.f / (d1 + 1e-8f);
            float s = r0 + r1;
            int q = q0 + qg * 4 + qj;
            idx_out[b * NBEF + q] = make_int2(j0, j1);
            w_out[b * NBEF + q]   = make_float2(r0 / s, r1 / s);
        }
    }
}

// ---------------- Kernel 1: merged one-time prep (A fragments + w_sp transpose) ----------------
__global__ __launch_bounds__(256) void prep_kernel(
    const float* __restrict__ w_ct,          // [128][128][4]
    const float* __restrict__ w_sp,          // [256][512]
    unsigned short* __restrict__ Aws,        // 65536 bf16
    float4* __restrict__ wTq,                // [128][256] (may be null)
    int do_wt)
{
    if (blockIdx.x < 32) {
        int g = blockIdx.x * 256 + threadIdx.x;  // 0..8191
        int lane = g & 63;
        int ks = (g >> 6) & 7;
        int mt16 = g >> 9;
        int m = mt16 * 16 + (lane & 15);
        int o = m & 127;
        int modd = (m >= 128);
        unsigned short t8[8];
        #pragma unroll
        for (int j = 0; j < 8; ++j) {
            int k = ks * 32 + (lane >> 4) * 8 + j;
            int i = k & 127;
            int tap = modd ? (k < 128 ? 2 : 0) : (k < 128 ? 3 : 1);
            t8[j] = f32_to_bf16(w_ct[((size_t)i * DNOUT + o) * 4 + tap]);
        }
        *reinterpret_cast<uint4*>(Aws + (size_t)g * 8) = *reinterpret_cast<const uint4*>(t8);
    } else if (do_wt) {
        int c4 = blockIdx.x - 32;                // 0..127
        int o  = threadIdx.x;                    // 0..255
        float4 v = *reinterpret_cast<const float4*>(w_sp + (size_t)o * SPIN + c4 * 4);
        wTq[c4 * 256 + o] = v;
    }
}

// ---------------- Kernel M: merged main — dense (x<128) + sparse (x 128..159) ----------------
// Dense path: barrier-free per-wave staging, ks-outer acc[9][2]-resident MFMA, seam-free
// full-line epilogue.  Sparse path: b128-vectorized fs + coalesced wTq, 2 groups x 8 n's.
// Co-scheduling lets sparse blocks fill dense's latency gaps.
__global__ __launch_bounds__(512, 4) void main_kernel(
    const float* __restrict__ DF,            // [16][128][256][32]
    const float* __restrict__ SF,            // [16][512][256]
    const unsigned short* __restrict__ Aws,  // fragment-linear A
    const float* __restrict__ w_sp,
    const float4* __restrict__ wTq,          // or null
    const float* __restrict__ b_ct,
    const float* __restrict__ gamma_dn,
    const float* __restrict__ beta_dn,
    const float* __restrict__ b_sp,
    const float* __restrict__ gamma_sp,
    const float* __restrict__ beta_sp,
    const int2* __restrict__ idxws, const float2* __restrict__ wgtws,
    float* __restrict__ out)                 // full output base
{
    __shared__ __align__(16) char smem[71808];
    int b   = blockIdx.y;
    int tid  = threadIdx.x;
    const float invs = 1.0f / sqrtf(1.0f + 1e-5f);

    if (blockIdx.x < 128) {
        // ================= DENSE path =================
        float* Y            = (float*)smem;                        // 32768 B
        unsigned short* Xs  = (unsigned short*)(smem + 32768);     // 37376 B
        float* bnb          = (float*)(smem + 70144);
        float* bns          = (float*)(smem + 70656);
        float* bnt          = (float*)(smem + 71168);
        int2*  sij          = (int2*)(smem + 71680);
        float2* swt         = (float2*)(smem + 71728);
        float* outd = out + SP_ELEMS;

        int blk = blockIdx.x;
        int n0  = blk * 4;
        int S0  = n0 * 32;
        int T0  = n0 * 64;
        int lane = tid & 63;
        int wid  = tid >> 6;
        int rit  = lane & 15;
        int kgrp = lane >> 4;

        if (tid < 128) {
            bnb[tid] = b_ct[tid];
            bns[tid] = gamma_dn[tid] * invs;
            bnt[tid] = beta_dn[tid];
        }
        if (tid < 6) {
            int s = n0 - 1 + tid;
            s = (s < 0) ? 0 : ((s > NBEF - 1) ? NBEF - 1 : s);
            sij[tid] = idxws[b * NBEF + s];
            swt[tid] = wgtws[b * NBEF + s];
        }
        if (tid < 256) {
            uint4 z = make_uint4(0, 0, 0, 0);
            *reinterpret_cast<uint4*>(&Xs[130 * 128 + tid * 8]) = z;
        }
        __syncthreads();                     // barrier 1

        const float* DFb = DF + (size_t)b * (DNIN * NSTK * NPNT);

        if (tid < 256) {                     // halo cols 0 and 129
            int i    = tid & 127;
            int side = tid >> 7;
            int col  = side ? 129 : 0;
            int L    = side ? (S0 + 128) : (S0 - 1);
            L = (L < 0) ? 0 : ((L > 16383) ? 16383 : L);
            int stroke = L >> 5, pt = L & 31;
            int slot = stroke - (n0 - 1);
            int2  ij = sij[slot];
            float2 w = swt[slot];
            float v = w.x * DFb[(size_t)i * 8192 + (size_t)ij.x * NPNT + pt]
                    + w.y * DFb[(size_t)i * 8192 + (size_t)ij.y * NPNT + pt];
            int dst = col * 128 + ((((i >> 3) ^ (col & 15))) << 3) + (i & 7);
            Xs[dst] = f32_to_bf16(v);
        }

        // barrier-free per-wave staging
        float* Ysl = &Y[wid * 1024];
        int swq = (lane & 7) ^ ((lane >> 3) & 7);
        int sp2 = lane & 31;
        int so  = lane >> 5;
        int goct = wid * 2 + so;
        #pragma unroll 1
        for (int nl = 0; nl < 4; ++nl) {
            int2 ij = sij[nl + 1];
            #pragma unroll
            for (int p = 0; p < 2; ++p) {
                int jj = p ? ij.y : ij.x;
                #pragma unroll
                for (int q = 0; q < 2; ++q) {
                    int i = 16 * wid + q * 8 + (lane >> 3);
                    const float* g = DFb + (size_t)i * 8192 + (size_t)jj * NPNT + (swq << 2);
                    __builtin_amdgcn_global_load_lds((gas1_t)(const void*)g,
                        (las3_t)(void*)&Ysl[p * 512 + q * 256], 16, 0, 0);
                }
            }
            asm volatile("s_waitcnt vmcnt(0)" ::: "memory");
            __builtin_amdgcn_sched_barrier(0);
            {
                float2 w = swt[nl + 1];
                unsigned short t8[8];
                #pragma unroll
                for (int pp = 0; pp < 8; ++pp) {
                    int a = (so * 8 + pp) * 32 + (((sp2 >> 2) ^ pp) << 2) + (sp2 & 3);
                    float v = w.x * Ysl[a] + w.y * Ysl[512 + a];
                    t8[pp] = f32_to_bf16(v);
                }
                int col = nl * 32 + sp2 + 1;
                int dst = col * 128 + ((goct ^ (col & 15)) << 3);
                *reinterpret_cast<uint4*>(&Xs[dst]) = *reinterpret_cast<const uint4*>(t8);
            }
        }
        __syncthreads();                     // barrier 2: Xs ready

        // MFMA: ks-outer / nt-inner, acc[9][2] resident
        f32x4v acc[9][2];
        #pragma unroll
        for (int nt = 0; nt < 9; ++nt) {
            acc[nt][0] = (f32x4v){0.f, 0.f, 0.f, 0.f};
            acc[nt][1] = (f32x4v){0.f, 0.f, 0.f, 0.f};
        }
        #pragma unroll
        for (int kh = 0; kh < 2; ++kh) {
            bf16x8v af[2][4];
            #pragma unroll
            for (int mt = 0; mt < 2; ++mt) {
                int mt16 = wid + mt * 8;
                #pragma unroll
                for (int k4 = 0; k4 < 4; ++k4) {
                    int ks = kh * 4 + k4;
                    af[mt][k4] = *reinterpret_cast<const bf16x8v*>(
                        Aws + (((size_t)(mt16 * 8 + ks)) * 64 + lane) * 8);
                }
            }
            #pragma unroll
            for (int k4 = 0; k4 < 4; ++k4) {
                int ks   = kh * 4 + k4;
                int kb   = ks * 32 + kgrp * 8;
                int half = kb >> 7;
                int i    = kb & 127;
                #pragma unroll
                for (int nt = 0; nt < 9; ++nt) {
                    int col = nt * 16 + rit + half;
                    int src = col * 128 + ((((i >> 3) ^ (col & 15))) << 3);
                    bf16x8v bfrag = *reinterpret_cast<const bf16x8v*>(&Xs[src]);
                    acc[nt][0] = __builtin_amdgcn_mfma_f32_16x16x32_bf16(af[0][k4], bfrag, acc[nt][0], 0, 0, 0);
                    acc[nt][1] = __builtin_amdgcn_mfma_f32_16x16x32_bf16(af[1][k4], bfrag, acc[nt][1], 0, 0, 0);
                }
            }
        }

        // seam-free epilogue
        int srcl = (lane & 48) | ((lane + 1) & 15);
        #pragma unroll
        for (int nt = 0; nt < 8; ++nt) {
            int c = nt * 16 + rit;
            #pragma unroll
            for (int q = 0; q < 4; ++q) {
                float srcv = (rit == 0) ? acc[nt + 1][1][q] : acc[nt][1][q];
                float a1n = __shfl(srcv, srcl, 64);
                int o = wid * 16 + kgrp * 4 + q;
                float bias = bnb[o], scale = bns[o], beta = bnt[o];
                float ye = fast_gelu((acc[nt][0][q] + bias) * scale + beta);
                float yo = fast_gelu((a1n + bias) * scale + beta);
                size_t rowbase = (((size_t)b * DNOUT + o) << 15) + (size_t)T0;
                *reinterpret_cast<float2*>(outd + rowbase + 2 * c) = make_float2(ye, yo);
            }
        }
    } else {
        // ================= SPARSE path (2 groups x 8 n's) =================
        float*  fsb  = (float*)smem;                      // fs[2][512][8] = 32768 B
        int2*   ssij = (int2*)(smem + 32768);             // [16]
        float2* sswt = (float2*)(smem + 32896);           // [16]

        int sx = blockIdx.x - 128;                        // 0..31
        int tid256 = tid & 255;
        int group  = tid >> 8;                            // 0/1
        int n0 = sx * 16 + group * 8;

        if (tid < 16) {
            ssij[tid] = idxws[b * NBEF + sx * 16 + tid];
            sswt[tid] = wgtws[b * NBEF + sx * 16 + tid];
        }
        __syncthreads();

        float* fsg = fsb + group * 4096;
        for (int l = tid256; l < SPIN * 8; l += 256) {
            int c = l >> 3, nn = l & 7;
            int2  ij = ssij[group * 8 + nn];
            float2 w = sswt[group * 8 + nn];
            const float* row = SF + ((size_t)b * SPIN + c) * NSTK;
            fsg[l] = w.x * row[ij.x] + w.y * row[ij.y];
        }
        __syncthreads();

        int o = tid256;
        float acc[8] = {0,0,0,0,0,0,0,0};
        #pragma unroll 2
        for (int c4 = 0; c4 < SPIN / 4; ++c4) {
            float4 a = wTq ? wTq[c4 * 256 + o]
                           : *reinterpret_cast<const float4*>(w_sp + (size_t)o * SPIN + c4 * 4);
            int c = c4 * 4;
            float4 fA[4], fB[4];
            #pragma unroll
            for (int k = 0; k < 4; ++k) {
                fA[k] = *reinterpret_cast<const float4*>(&fsg[(c + k) * 8]);
                fB[k] = *reinterpret_cast<const float4*>(&fsg[(c + k) * 8 + 4]);
            }
            const float* a4 = reinterpret_cast<const float*>(&a);
            #pragma unroll
            for (int nn = 0; nn < 4; ++nn) {
                float sA = 0.f, sB = 0.f;
                #pragma unroll
                for (int k = 0; k < 4; ++k) {
                    sA += a4[k] * reinterpret_cast<const float*>(&fA[k])[nn];
                    sB += a4[k] * reinterpret_cast<const float*>(&fB[k])[nn];
                }
                acc[nn]     += sA;
                acc[nn + 4] += sB;
            }
        }

        float bias  = b_sp[o];
        float scale = gamma_sp[o] * invs;
        float beta  = beta_sp[o];
        float r[8];
        #pragma unroll
        for (int q = 0; q < 8; ++q)
            r[q] = fast_gelu((acc[q] + bias) * scale + beta);
        float* dst = out + ((size_t)b * SPOUT + o) * NBEF + n0;
        *reinterpret_cast<float4*>(dst)     = make_float4(r[0], r[1], r[2], r[3]);
        *reinterpret_cast<float4*>(dst + 4) = make_float4(r[4], r[5], r[6], r[7]);
    }
}

extern "C" void kernel_launch(void* const* d_in, const int* in_sizes, int n_in,
                              void* d_out, int out_size, void* d_ws, size_t ws_size,
                              hipStream_t stream) {
    const float* sparse_fea   = (const float*)d_in[0];
    const float* dense_fea    = (const float*)d_in[1];
    const float* stk_coor     = (const float*)d_in[2];
    const float* stk_coor_bef = (const float*)d_in[3];
    const float* w_sp     = (const float*)d_in[4];
    const float* b_sp     = (const float*)d_in[5];
    const float* gamma_sp = (const float*)d_in[6];
    const float* beta_sp  = (const float*)d_in[7];
    const float* w_ct     = (const float*)d_in[8];
    const float* b_ct     = (const float*)d_in[9];
    const float* gamma_dn = (const float*)d_in[10];
    const float* beta_dn  = (const float*)d_in[11];
    float* out = (float*)d_out;

    char* ws = (char*)d_ws;
    int2*   idx = (int2*)ws;                               // 64 KB
    float2* wgt = (float2*)(ws + 65536);                   // 64 KB
    unsigned short* Aws = (unsigned short*)(ws + 131072);  // 128 KB
    bool use_wt = (ws_size >= 786432);                     // + 512 KB wTq = 768 KB total
    float4* wTq = use_wt ? (float4*)(ws + 262144) : nullptr;

    knn_kernel<<<dim3(NBEF / 16, NB), 256, 0, stream>>>(stk_coor, stk_coor_bef, idx, wgt);
    prep_kernel<<<use_wt ? 160 : 32, 256, 0, stream>>>(w_ct, w_sp, Aws, wTq, use_wt ? 1 : 0);
    main_kernel<<<dim3(160, NB), 512, 0, stream>>>(
        dense_fea, sparse_fea, Aws, w_sp, wTq,
        b_ct, gamma_dn, beta_dn, b_sp, gamma_sp, beta_sp,
        idx, wgt, out);
}